// Round 1
// baseline (811.765 us; speedup 1.0000x reference)
//
#include <hip/hip_runtime.h>

// DecoderCell (LFADS-style) fused MI355X implementation.
// B=32768, CI=128, GEN=512, CON=256, CO=64, FAC=128. All in/out f32.
// h_0 layout: [gen 0:512 | con 512:768 | mean 768:832 | std 832:896 | gi 896:960 | factor 960:1088]

typedef short  s16x8 __attribute__((ext_vector_type(8)));
typedef float  f32x4 __attribute__((ext_vector_type(4)));
typedef _Float16 f16x4 __attribute__((ext_vector_type(4)));

#define OUTP 1088

__device__ __forceinline__ unsigned short f2bf(float f) {
  union { float f; unsigned int u; } v; v.f = f;
  unsigned int u = v.u;
  return (unsigned short)((u + 0x7FFFu + ((u >> 16) & 1u)) >> 16);  // RNE
}
__device__ __forceinline__ float sigm(float x) { return 1.f / (1.f + __expf(-x)); }
__device__ __forceinline__ float tanh_(float x) { return 2.f / (1.f + __expf(-2.f * x)) - 1.f; }

__device__ __forceinline__ f32x4 mfma16(s16x8 a, s16x8 b, f32x4 c) {
  return __builtin_amdgcn_mfma_f32_16x16x32_bf16(a, b, c, 0, 0, 0);
}
__device__ __forceinline__ s16x8 ldb8(const unsigned short* p) {
  return *reinterpret_cast<const s16x8*>(p);
}
// 8 contiguous f32 -> bf16x8 fragment
__device__ __forceinline__ s16x8 cvt8(const float* p) {
  float4 a = *reinterpret_cast<const float4*>(p);
  float4 b = *reinterpret_cast<const float4*>(p + 4);
  s16x8 r;
  r[0] = (short)f2bf(a.x); r[1] = (short)f2bf(a.y);
  r[2] = (short)f2bf(a.z); r[3] = (short)f2bf(a.w);
  r[4] = (short)f2bf(b.x); r[5] = (short)f2bf(b.y);
  r[6] = (short)f2bf(b.z); r[7] = (short)f2bf(b.w);
  return r;
}

// ---- prep: f32 -> bf16 weight conversion -----------------------------------
__global__ void cvt_kernel(const float* __restrict__ src, unsigned short* __restrict__ dst, int n4) {
  int i = blockIdx.x * 256 + threadIdx.x;
  if (i >= n4) return;
  float4 v = reinterpret_cast<const float4*>(src)[i];
  ushort4 o;
  o.x = f2bf(v.x); o.y = f2bf(v.y); o.z = f2bf(v.z); o.w = f2bf(v.w);
  reinterpret_cast<ushort4*>(dst)[i] = o;
}

// ---- prep: row-L2-normalize fac_W (128x512) -> bf16 ------------------------
__global__ void facnorm_kernel(const float* __restrict__ w, unsigned short* __restrict__ dst) {
  int row = blockIdx.x;       // 128
  int lane = threadIdx.x;     // 64 (one wave)
  float v[8]; float s = 0.f;
  #pragma unroll
  for (int i = 0; i < 8; ++i) { v[i] = w[row * 512 + lane * 8 + i]; s += v[i] * v[i]; }
  #pragma unroll
  for (int off = 32; off; off >>= 1) s += __shfl_xor(s, off);
  float scale = 1.f / fmaxf(sqrtf(s), 1e-12f);
  #pragma unroll
  for (int i = 0; i < 8; ++i) dst[row * 512 + lane * 8 + i] = f2bf(v[i] * scale);
}

// ---- controller GRU + co-linear + rsample ----------------------------------
// 64 rows/block, 4 waves; wave w owns rows w*16..w*16+15, all 16 j-tiles.
#define CP 264   // 256 + 8 pad (breaks ds_read_b128 bank conflict)
__global__ __launch_bounds__(256) void con_kernel(
    const float* __restrict__ input, const float* __restrict__ h0,
    const float* __restrict__ eps,
    const unsigned short* __restrict__ wih, const unsigned short* __restrict__ whh,
    const unsigned short* __restrict__ coW,
    const float* __restrict__ bih, const float* __restrict__ bhh,
    const float* __restrict__ cob,
    float* __restrict__ out, unsigned short* __restrict__ gi)
{
  __shared__ unsigned short h_lds[64 * CP];
  __shared__ unsigned short rh_lds[64 * CP];
  const int tid = threadIdx.x;
  const int row0 = blockIdx.x * 64;

  // stage old con_state (h_0 cols 512..767) as bf16
  #pragma unroll
  for (int i = 0; i < 16; ++i) {
    int lin = i * 256 + tid;
    int r = lin >> 6;
    int c = (lin & 63) * 4;
    float4 v = *reinterpret_cast<const float4*>(&h0[(size_t)(row0 + r) * OUTP + 512 + c]);
    unsigned short* p = &h_lds[r * CP + c];
    p[0] = f2bf(v.x); p[1] = f2bf(v.y); p[2] = f2bf(v.z); p[3] = f2bf(v.w);
  }
  __syncthreads();

  const int w = tid >> 6, lane = tid & 63;
  const int ln = lane & 15, lk = lane >> 4;
  const int mrow = w * 16 + ln;                 // A-fragment row (LDS)
  const size_t arow = (size_t)(row0 + w * 16 + ln);
  const int drow = w * 16 + lk * 4;             // D rows base (LDS)
  const size_t drow_g = (size_t)(row0 + drow);

  // cache con_input fragments: X = [input(256) | factor(128)], K=384 -> 12 frags
  s16x8 xf[12];
  #pragma unroll
  for (int kt = 0; kt < 12; ++kt) {
    int k0 = kt * 32 + lk * 8;
    const float* src = (kt < 8) ? &input[arow * 256 + k0]
                                : &h0[arow * OUTP + 960 + (k0 - 256)];
    xf[kt] = cvt8(src);
  }

  f16x4 zs[16], xns[16];
  #pragma unroll
  for (int jt = 0; jt < 16; ++jt) {
    const int jc = jt * 16 + ln;
    f32x4 xz = {0,0,0,0}, xr = {0,0,0,0}, xn = {0,0,0,0}, hz = {0,0,0,0}, hr = {0,0,0,0};
    #pragma unroll
    for (int kt = 0; kt < 12; ++kt) {
      int k0 = kt * 32 + lk * 8;
      s16x8 bz = ldb8(&wih[(size_t)jc * 384 + k0]);
      s16x8 br = ldb8(&wih[(size_t)(256 + jc) * 384 + k0]);
      s16x8 bn = ldb8(&wih[(size_t)(512 + jc) * 384 + k0]);
      xz = mfma16(xf[kt], bz, xz);
      xr = mfma16(xf[kt], br, xr);
      xn = mfma16(xf[kt], bn, xn);
    }
    #pragma unroll
    for (int kt = 0; kt < 8; ++kt) {
      int k0 = kt * 32 + lk * 8;
      s16x8 a  = ldb8(&h_lds[mrow * CP + k0]);
      s16x8 bz = ldb8(&whh[(size_t)jc * 256 + k0]);
      s16x8 br = ldb8(&whh[(size_t)(256 + jc) * 256 + k0]);
      hz = mfma16(a, bz, hz);
      hr = mfma16(a, br, hr);
    }
    float bz_ = bih[jc] + bhh[jc];
    float br_ = bih[256 + jc] + bhh[256 + jc];
    float bn_ = bih[512 + jc];
    #pragma unroll
    for (int r = 0; r < 4; ++r) {
      float z  = sigm(xz[r] + hz[r] + bz_);
      float rr = sigm(xr[r] + hr[r] + br_);
      float h  = h0[(drow_g + r) * OUTP + 512 + jc];   // exact f32 h
      rh_lds[(drow + r) * CP + jc] = f2bf(rr * h);
      zs[jt][r]  = (_Float16)z;
      xns[jt][r] = (_Float16)(xn[r] + bn_);
    }
  }
  __syncthreads();

  // hn GEMM + gate combine; h_new -> out + h_lds (bf16, own rows only)
  #pragma unroll
  for (int jt = 0; jt < 16; ++jt) {
    const int jc = jt * 16 + ln;
    f32x4 hn = {0,0,0,0};
    #pragma unroll
    for (int kt = 0; kt < 8; ++kt) {
      int k0 = kt * 32 + lk * 8;
      s16x8 a = ldb8(&rh_lds[mrow * CP + k0]);
      s16x8 b = ldb8(&whh[(size_t)(512 + jc) * 256 + k0]);
      hn = mfma16(a, b, hn);
    }
    float bn2 = bhh[512 + jc];
    #pragma unroll
    for (int r = 0; r < 4; ++r) {
      float n = tanh_((float)xns[jt][r] + hn[r] + bn2);
      float h = h0[(drow_g + r) * OUTP + 512 + jc];
      float z = (float)zs[jt][r];
      float hv = z * h + (1.f - z) * n;
      hv = fminf(fmaxf(hv, -5.f), 5.f);
      out[(drow_g + r) * OUTP + 512 + jc] = hv;
      h_lds[(drow + r) * CP + jc] = f2bf(hv);          // now h_lds = h_new
    }
  }

  // co-linear + std + rsample (own rows only -> no barrier needed)
  #pragma unroll
  for (int jt = 0; jt < 4; ++jt) {
    const int j = jt * 16 + ln;       // 0..63
    f32x4 am = {0,0,0,0}, av = {0,0,0,0};
    #pragma unroll
    for (int kt = 0; kt < 8; ++kt) {
      int k0 = kt * 32 + lk * 8;
      s16x8 a  = ldb8(&h_lds[mrow * CP + k0]);
      s16x8 bm = ldb8(&coW[(size_t)j * 256 + k0]);
      s16x8 bv = ldb8(&coW[(size_t)(64 + j) * 256 + k0]);
      am = mfma16(a, bm, am);
      av = mfma16(a, bv, av);
    }
    float bm_ = cob[j], bv_ = cob[64 + j];
    #pragma unroll
    for (int r = 0; r < 4; ++r) {
      float mean = am[r] + bm_;
      float sd = __expf(0.5f * (av[r] + bv_));
      float e = eps[(drow_g + r) * 64 + j];
      float gival = mean + sd * e;
      size_t ob = (drow_g + r) * OUTP;
      out[ob + 768 + j] = mean;
      out[ob + 832 + j] = sd;
      out[ob + 896 + j] = gival;
      gi[(drow_g + r) * 64 + j] = f2bf(gival);
    }
  }
}

// ---- generator GRU + factor linear -----------------------------------------
// 64 rows/block, 8 waves; wave w: M-tile mt=w>>1, j-half jh=w&1 (16 j-tiles each).
#define GP 520   // 512 + 8 pad
__global__ __launch_bounds__(512) void gen_kernel(
    const float* __restrict__ h0, const unsigned short* __restrict__ gi,
    const unsigned short* __restrict__ wih, const unsigned short* __restrict__ whh,
    const unsigned short* __restrict__ facw,
    const float* __restrict__ bih, const float* __restrict__ bhh,
    float* __restrict__ out)
{
  __shared__ unsigned short h_lds[64 * GP];
  __shared__ unsigned short rh_lds[64 * GP];
  const int tid = threadIdx.x;
  const int row0 = blockIdx.x * 64;

  // stage old gen_state (h_0 cols 0..511) as bf16
  #pragma unroll
  for (int i = 0; i < 16; ++i) {
    int lin = i * 512 + tid;
    int r = lin >> 7;
    int c = (lin & 127) * 4;
    float4 v = *reinterpret_cast<const float4*>(&h0[(size_t)(row0 + r) * OUTP + c]);
    unsigned short* p = &h_lds[r * GP + c];
    p[0] = f2bf(v.x); p[1] = f2bf(v.y); p[2] = f2bf(v.z); p[3] = f2bf(v.w);
  }
  __syncthreads();

  const int w = tid >> 6, lane = tid & 63;
  const int ln = lane & 15, lk = lane >> 4;
  const int mt = w >> 1, jh = w & 1;
  const int mrow = mt * 16 + ln;
  const size_t arow = (size_t)(row0 + mt * 16 + ln);
  const int drow = mt * 16 + lk * 4;
  const size_t drow_g = (size_t)(row0 + drow);

  // cache gen_input fragments (K=64 -> 2)
  s16x8 xf[2];
  #pragma unroll
  for (int kt = 0; kt < 2; ++kt)
    xf[kt] = ldb8(&gi[arow * 64 + kt * 32 + lk * 8]);

  f16x4 zs[16], xns[16];
  #pragma unroll
  for (int jl = 0; jl < 16; ++jl) {
    const int jc = (jh * 16 + jl) * 16 + ln;   // 0..511
    f32x4 xz = {0,0,0,0}, xr = {0,0,0,0}, xn = {0,0,0,0}, hz = {0,0,0,0}, hr = {0,0,0,0};
    #pragma unroll
    for (int kt = 0; kt < 2; ++kt) {
      int k0 = kt * 32 + lk * 8;
      s16x8 bz = ldb8(&wih[(size_t)jc * 64 + k0]);
      s16x8 br = ldb8(&wih[(size_t)(512 + jc) * 64 + k0]);
      s16x8 bn = ldb8(&wih[(size_t)(1024 + jc) * 64 + k0]);
      xz = mfma16(xf[kt], bz, xz);
      xr = mfma16(xf[kt], br, xr);
      xn = mfma16(xf[kt], bn, xn);
    }
    #pragma unroll
    for (int kt = 0; kt < 16; ++kt) {
      int k0 = kt * 32 + lk * 8;
      s16x8 a  = ldb8(&h_lds[mrow * GP + k0]);
      s16x8 bz = ldb8(&whh[(size_t)jc * 512 + k0]);
      s16x8 br = ldb8(&whh[(size_t)(512 + jc) * 512 + k0]);
      hz = mfma16(a, bz, hz);
      hr = mfma16(a, br, hr);
    }
    float bz_ = bih[jc] + bhh[jc];
    float br_ = bih[512 + jc] + bhh[512 + jc];
    float bn_ = bih[1024 + jc];
    #pragma unroll
    for (int r = 0; r < 4; ++r) {
      float z  = sigm(xz[r] + hz[r] + bz_);
      float rr = sigm(xr[r] + hr[r] + br_);
      float h  = h0[(drow_g + r) * OUTP + jc];
      rh_lds[(drow + r) * GP + jc] = f2bf(rr * h);
      zs[jl][r]  = (_Float16)z;
      xns[jl][r] = (_Float16)(xn[r] + bn_);
    }
  }
  __syncthreads();

  #pragma unroll
  for (int jl = 0; jl < 16; ++jl) {
    const int jc = (jh * 16 + jl) * 16 + ln;
    f32x4 hn = {0,0,0,0};
    #pragma unroll
    for (int kt = 0; kt < 16; ++kt) {
      int k0 = kt * 32 + lk * 8;
      s16x8 a = ldb8(&rh_lds[mrow * GP + k0]);
      s16x8 b = ldb8(&whh[(size_t)(1024 + jc) * 512 + k0]);
      hn = mfma16(a, b, hn);
    }
    float bn2 = bhh[1024 + jc];
    #pragma unroll
    for (int r = 0; r < 4; ++r) {
      float n = tanh_((float)xns[jl][r] + hn[r] + bn2);
      float h = h0[(drow_g + r) * OUTP + jc];
      float z = (float)zs[jl][r];
      float hv = z * h + (1.f - z) * n;
      hv = fminf(fmaxf(hv, -5.f), 5.f);
      out[(drow_g + r) * OUTP + jc] = hv;
      h_lds[(drow + r) * GP + jc] = f2bf(hv);          // h_lds = gen_state_new
    }
  }
  __syncthreads();   // factor needs all columns of h_new

  #pragma unroll
  for (int jl = 0; jl < 4; ++jl) {
    const int jc = jh * 64 + jl * 16 + ln;   // 0..127
    f32x4 acc = {0,0,0,0};
    #pragma unroll
    for (int kt = 0; kt < 16; ++kt) {
      int k0 = kt * 32 + lk * 8;
      s16x8 a = ldb8(&h_lds[mrow * GP + k0]);
      s16x8 b = ldb8(&facw[(size_t)jc * 512 + k0]);
      acc = mfma16(a, b, acc);
    }
    #pragma unroll
    for (int r = 0; r < 4; ++r)
      out[(drow_g + r) * OUTP + 960 + jc] = acc[r];
  }
}

extern "C" void kernel_launch(void* const* d_in, const int* in_sizes, int n_in,
                              void* d_out, int out_size, void* d_ws, size_t ws_size,
                              hipStream_t stream) {
  const float* input   = (const float*)d_in[0];
  const float* h0      = (const float*)d_in[1];
  const float* eps     = (const float*)d_in[2];
  const float* gen_Wih = (const float*)d_in[3];
  const float* gen_bih = (const float*)d_in[4];
  const float* gen_Whh = (const float*)d_in[5];
  const float* gen_bhh = (const float*)d_in[6];
  const float* con_Wih = (const float*)d_in[7];
  const float* con_bih = (const float*)d_in[8];
  const float* con_Whh = (const float*)d_in[9];
  const float* con_bhh = (const float*)d_in[10];
  const float* fac_W   = (const float*)d_in[11];
  const float* co_W    = (const float*)d_in[12];
  const float* co_b    = (const float*)d_in[13];
  float* out = (float*)d_out;

  unsigned short* ws = (unsigned short*)d_ws;
  unsigned short* w_conWih = ws;                       // 768*384
  unsigned short* w_conWhh = w_conWih + 768 * 384;     // 768*256
  unsigned short* w_genWih = w_conWhh + 768 * 256;     // 1536*64
  unsigned short* w_genWhh = w_genWih + 1536 * 64;     // 1536*512
  unsigned short* w_coW    = w_genWhh + 1536 * 512;    // 128*256
  unsigned short* w_facWn  = w_coW + 128 * 256;        // 128*512
  unsigned short* w_gi     = w_facWn + 128 * 512;      // 32768*64

  cvt_kernel<<<(768 * 384 / 4 + 255) / 256, 256, 0, stream>>>(con_Wih, w_conWih, 768 * 384 / 4);
  cvt_kernel<<<(768 * 256 / 4 + 255) / 256, 256, 0, stream>>>(con_Whh, w_conWhh, 768 * 256 / 4);
  cvt_kernel<<<(1536 * 64 / 4 + 255) / 256, 256, 0, stream>>>(gen_Wih, w_genWih, 1536 * 64 / 4);
  cvt_kernel<<<(1536 * 512 / 4 + 255) / 256, 256, 0, stream>>>(gen_Whh, w_genWhh, 1536 * 512 / 4);
  cvt_kernel<<<(128 * 256 / 4 + 255) / 256, 256, 0, stream>>>(co_W, w_coW, 128 * 256 / 4);
  facnorm_kernel<<<128, 64, 0, stream>>>(fac_W, w_facWn);

  con_kernel<<<512, 256, 0, stream>>>(input, h0, eps, w_conWih, w_conWhh, w_coW,
                                      con_bih, con_bhh, co_b, out, w_gi);
  gen_kernel<<<512, 512, 0, stream>>>(h0, w_gi, w_genWih, w_genWhh, w_facWn,
                                      gen_bih, gen_bhh, out);
}

// Round 2
// 567.294 us; speedup vs baseline: 1.4309x; 1.4309x over previous
//
#include <hip/hip_runtime.h>

// DecoderCell (LFADS-style) fused MI355X implementation, v2.
// B=32768, CI=128, GEN=512, CON=256, CO=64, FAC=128. All in/out f32.
// h_0 layout: [gen 0:512 | con 512:768 | mean 768:832 | std 832:896 | gi 896:960 | factor 960:1088]
//
// Structure: concat-K GRU. Phase1: z,r = sigm([h|x] @ [Whh|Wih]^T + b). rh
// overwrites the h-section of the single LDS A-buffer; Phase2: n = tanh(
// [rh|x] @ [Whh_n|Wih_n]^T + b) (xn folded in via K-concat). 32 rows/block,
// 8 waves, mfma 32x32x16. z/h/h_new live in packed f16 regs across barriers.

typedef short  s16x8  __attribute__((ext_vector_type(8)));
typedef float  f32x4  __attribute__((ext_vector_type(4)));
typedef float  f32x16 __attribute__((ext_vector_type(16)));
typedef _Float16 f16x4 __attribute__((ext_vector_type(4)));

#define OUTP 1088

__device__ __forceinline__ unsigned short f2bf(float f) {
  union { float f; unsigned int u; } v; v.f = f;
  unsigned int u = v.u;
  return (unsigned short)((u + 0x7FFFu + ((u >> 16) & 1u)) >> 16);  // RNE
}
__device__ __forceinline__ float bf2f(unsigned short b) {
  union { unsigned int u; float f; } v; v.u = ((unsigned int)b) << 16;
  return v.f;
}
__device__ __forceinline__ float sigm(float x) { return 1.f / (1.f + __expf(-x)); }
__device__ __forceinline__ float tanh_(float x) { return 2.f / (1.f + __expf(-2.f * x)) - 1.f; }

__device__ __forceinline__ f32x4 mfma16(s16x8 a, s16x8 b, f32x4 c) {
  return __builtin_amdgcn_mfma_f32_16x16x32_bf16(a, b, c, 0, 0, 0);
}
__device__ __forceinline__ f32x16 mfma32(s16x8 a, s16x8 b, f32x16 c) {
  return __builtin_amdgcn_mfma_f32_32x32x16_bf16(a, b, c, 0, 0, 0);
}
template <typename T>
__device__ __forceinline__ s16x8 ldb8(const T* p) {
  return *reinterpret_cast<const s16x8*>(p);
}

// ---- prep: f32 -> bf16 plain conversion -------------------------------------
__global__ void cvt_kernel(const float* __restrict__ src, unsigned short* __restrict__ dst, int n4) {
  int i = blockIdx.x * 256 + threadIdx.x;
  if (i >= n4) return;
  float4 v = reinterpret_cast<const float4*>(src)[i];
  ushort4 o;
  o.x = f2bf(v.x); o.y = f2bf(v.y); o.z = f2bf(v.z); o.w = f2bf(v.w);
  reinterpret_cast<ushort4*>(dst)[i] = o;
}

// ---- prep: row-L2-normalize fac_W (128x512) -> bf16 -------------------------
__global__ void facnorm_kernel(const float* __restrict__ w, unsigned short* __restrict__ dst) {
  int row = blockIdx.x;       // 128
  int lane = threadIdx.x;     // 64
  float v[8]; float s = 0.f;
  #pragma unroll
  for (int i = 0; i < 8; ++i) { v[i] = w[row * 512 + lane * 8 + i]; s += v[i] * v[i]; }
  #pragma unroll
  for (int off = 32; off; off >>= 1) s += __shfl_xor(s, off);
  float scale = 1.f / fmaxf(sqrtf(s), 1e-12f);
  #pragma unroll
  for (int i = 0; i < 8; ++i) dst[row * 512 + lane * 8 + i] = f2bf(v[i] * scale);
}

// ---- prep: pack gen weights ---------------------------------------------------
// genB1[1024][576]: row j<512: [Whh_z[j] | Wih_z[j]] ; row 512+j: r-gate.
// genB2[512][576]:  [Whh_n[j] | Wih_n[j]].
__global__ void genpack_kernel(const float* __restrict__ whh, const float* __restrict__ wih,
                               unsigned short* __restrict__ B1, unsigned short* __restrict__ B2) {
  int r = blockIdx.x;          // 0..1535
  int c4 = threadIdx.x * 4;    // 0..572
  float4 v;
  if (c4 < 512) v = *reinterpret_cast<const float4*>(&whh[(size_t)r * 512 + c4]);
  else          v = *reinterpret_cast<const float4*>(&wih[(size_t)r * 64 + (c4 - 512)]);
  ushort4 o; o.x = f2bf(v.x); o.y = f2bf(v.y); o.z = f2bf(v.z); o.w = f2bf(v.w);
  unsigned short* dst = (r < 1024) ? &B1[(size_t)r * 576 + c4]
                                   : &B2[(size_t)(r - 1024) * 576 + c4];
  *reinterpret_cast<ushort4*>(dst) = o;
}

// ---- prep: pack con weights ---------------------------------------------------
// K-order = [input(256) | h(256) | factor(128)].
// conB1[512][640] (z rows 0:256, r rows 256:512), conB2[256][640] (n).
__global__ void conpack_kernel(const float* __restrict__ wih, const float* __restrict__ whh,
                               unsigned short* __restrict__ B1, unsigned short* __restrict__ B2) {
  int r = blockIdx.x;          // 0..767
  int c4 = threadIdx.x * 4;    // 0..636
  float4 v;
  if (c4 < 256)      v = *reinterpret_cast<const float4*>(&wih[(size_t)r * 384 + c4]);
  else if (c4 < 512) v = *reinterpret_cast<const float4*>(&whh[(size_t)r * 256 + (c4 - 256)]);
  else               v = *reinterpret_cast<const float4*>(&wih[(size_t)r * 384 + (c4 - 256)]);
  ushort4 o; o.x = f2bf(v.x); o.y = f2bf(v.y); o.z = f2bf(v.z); o.w = f2bf(v.w);
  unsigned short* dst = (r < 512) ? &B1[(size_t)r * 640 + c4]
                                  : &B2[(size_t)(r - 512) * 640 + c4];
  *reinterpret_cast<ushort4*>(dst) = o;
}

#define ROW32(v, lh) (((v) & 3) + 8 * ((v) >> 2) + 4 * (lh))

// ---- controller GRU + co-linear + rsample -----------------------------------
// 32 rows/block, 8 waves. A_lds[32][648] = [input(0:256)|h/rh/hnew(256:512)|factor(512:640)].
#define CPITCH 648   // stride 1296B = 81 x16B groups, 81%8==1 -> conflict-free rotation
__global__ __launch_bounds__(512, 4) void con_kernel(
    const float* __restrict__ input, const float* __restrict__ h0,
    const float* __restrict__ eps,
    const unsigned short* __restrict__ B1, const unsigned short* __restrict__ B2,
    const unsigned short* __restrict__ coW,
    const float* __restrict__ bih, const float* __restrict__ bhh,
    const float* __restrict__ cob,
    float* __restrict__ out, unsigned short* __restrict__ gi)
{
  __shared__ unsigned short A[32 * CPITCH];
  const int tid = threadIdx.x;
  const int row0 = blockIdx.x * 32;

  // ---- stage A = [input | h | factor] as bf16
  #pragma unroll
  for (int i = 0; i < 4; ++i) {   // input 32x256
    int lin = i * 512 + tid; int r = lin >> 6, c = (lin & 63) * 4;
    float4 v = *reinterpret_cast<const float4*>(&input[(size_t)(row0 + r) * 256 + c]);
    ushort4 o = { f2bf(v.x), f2bf(v.y), f2bf(v.z), f2bf(v.w) };
    *reinterpret_cast<ushort4*>(&A[r * CPITCH + c]) = o;
  }
  #pragma unroll
  for (int i = 0; i < 4; ++i) {   // h 32x256 (h0 cols 512:768)
    int lin = i * 512 + tid; int r = lin >> 6, c = (lin & 63) * 4;
    float4 v = *reinterpret_cast<const float4*>(&h0[(size_t)(row0 + r) * OUTP + 512 + c]);
    ushort4 o = { f2bf(v.x), f2bf(v.y), f2bf(v.z), f2bf(v.w) };
    *reinterpret_cast<ushort4*>(&A[r * CPITCH + 256 + c]) = o;
  }
  #pragma unroll
  for (int i = 0; i < 2; ++i) {   // factor 32x128 (h0 cols 960:1088)
    int lin = i * 512 + tid; int r = lin >> 5, c = (lin & 31) * 4;
    float4 v = *reinterpret_cast<const float4*>(&h0[(size_t)(row0 + r) * OUTP + 960 + c]);
    ushort4 o = { f2bf(v.x), f2bf(v.y), f2bf(v.z), f2bf(v.w) };
    *reinterpret_cast<ushort4*>(&A[r * CPITCH + 512 + c]) = o;
  }
  __syncthreads();

  const int w = tid >> 6, lane = tid & 63;
  const int lc = lane & 31, lh = lane >> 5;
  const int kofs = lh * 8;
  const int jc = w * 32 + lc;          // 0..255

  // ---- phase 1: z, r  (K=640 over [input|h|factor])
  f16x4 zreg[4], hreg[4];
  unsigned int rhp[8];
  {
    f32x16 zacc = {}, racc = {};
    #pragma unroll
    for (int kt = 0; kt < 40; ++kt) {
      int k0 = kt * 16 + kofs;
      s16x8 a  = ldb8(&A[lc * CPITCH + k0]);
      s16x8 bz = ldb8(&B1[(size_t)jc * 640 + k0]);
      s16x8 br = ldb8(&B1[(size_t)(256 + jc) * 640 + k0]);
      zacc = mfma32(a, bz, zacc);
      racc = mfma32(a, br, racc);
    }
    float bz_ = bih[jc] + bhh[jc];
    float br_ = bih[256 + jc] + bhh[256 + jc];
    #pragma unroll
    for (int v = 0; v < 16; ++v) {
      int rrow = ROW32(v, lh);
      float z  = sigm(zacc[v] + bz_);
      float rv = sigm(racc[v] + br_);
      float h  = bf2f(A[rrow * CPITCH + 256 + jc]);
      zreg[v >> 2][v & 3] = (_Float16)z;
      hreg[v >> 2][v & 3] = (_Float16)h;
      unsigned short rb = f2bf(rv * h);
      if (v & 1) rhp[v >> 1] |= ((unsigned int)rb << 16);
      else       rhp[v >> 1]  = rb;
    }
  }
  __syncthreads();
  #pragma unroll
  for (int v = 0; v < 16; ++v) {   // rh overwrites h section
    int rrow = ROW32(v, lh);
    unsigned short rb = (v & 1) ? (unsigned short)(rhp[v >> 1] >> 16)
                                : (unsigned short)(rhp[v >> 1] & 0xffffu);
    A[rrow * CPITCH + 256 + jc] = rb;
  }
  __syncthreads();

  // ---- phase 2: n = tanh([input|rh|factor] @ B2 + b) ; gate; h_new
  {
    f32x16 acc0 = {}, acc1 = {};
    #pragma unroll
    for (int kt = 0; kt < 40; kt += 2) {
      int k0 = kt * 16 + kofs;
      s16x8 a0 = ldb8(&A[lc * CPITCH + k0]);
      s16x8 b0 = ldb8(&B2[(size_t)jc * 640 + k0]);
      acc0 = mfma32(a0, b0, acc0);
      s16x8 a1 = ldb8(&A[lc * CPITCH + k0 + 16]);
      s16x8 b1 = ldb8(&B2[(size_t)jc * 640 + k0 + 16]);
      acc1 = mfma32(a1, b1, acc1);
    }
    float bn_ = bih[512 + jc] + bhh[512 + jc];
    #pragma unroll
    for (int v = 0; v < 16; ++v) {
      int rrow = ROW32(v, lh);
      float n = tanh_(acc0[v] + acc1[v] + bn_);
      float z = (float)zreg[v >> 2][v & 3];
      float h = (float)hreg[v >> 2][v & 3];
      float hv = fminf(fmaxf(z * h + (1.f - z) * n, -5.f), 5.f);
      out[(size_t)(row0 + rrow) * OUTP + 512 + jc] = hv;
      unsigned short hb = f2bf(hv);
      if (v & 1) rhp[v >> 1] = (rhp[v >> 1] & 0x0000ffffu) | ((unsigned int)hb << 16);
      else       rhp[v >> 1] = (rhp[v >> 1] & 0xffff0000u) | hb;
    }
  }
  __syncthreads();
  #pragma unroll
  for (int v = 0; v < 16; ++v) {   // h_new overwrites rh section
    int rrow = ROW32(v, lh);
    unsigned short hb = (v & 1) ? (unsigned short)(rhp[v >> 1] >> 16)
                                : (unsigned short)(rhp[v >> 1] & 0xffffu);
    A[rrow * CPITCH + 256 + jc] = hb;
  }
  __syncthreads();

  // ---- co-linear (K=256 over h_new), mean/std -> out + LDS f32 scratch
  float* co_f32 = reinterpret_cast<float*>(A);   // row stride 324 f32; cols 0:128 (input section, dead)
  {
    const int ln = lane & 15, lk = lane >> 4;
    const int jcc = w * 16 + ln;       // 0..127
    f32x4 acc[2] = {{0,0,0,0},{0,0,0,0}};
    #pragma unroll
    for (int kt = 0; kt < 8; ++kt) {
      int k0 = kt * 32 + lk * 8;
      s16x8 b = ldb8(&coW[(size_t)jcc * 256 + k0]);
      #pragma unroll
      for (int mt = 0; mt < 2; ++mt) {
        s16x8 a = ldb8(&A[(mt * 16 + ln) * CPITCH + 256 + k0]);
        acc[mt] = mfma16(a, b, acc[mt]);
      }
    }
    float cb = cob[jcc];
    #pragma unroll
    for (int mt = 0; mt < 2; ++mt) {
      #pragma unroll
      for (int rr = 0; rr < 4; ++rr) {
        int rrow = mt * 16 + lk * 4 + rr;
        float val = acc[mt][rr] + cb;
        if (jcc < 64) {   // mean
          out[(size_t)(row0 + rrow) * OUTP + 768 + jcc] = val;
          co_f32[rrow * 324 + jcc] = val;
        } else {          // std
          float sd = __expf(0.5f * val);
          out[(size_t)(row0 + rrow) * OUTP + 832 + (jcc - 64)] = sd;
          co_f32[rrow * 324 + jcc] = sd;
        }
      }
    }
  }
  __syncthreads();

  // ---- rsample: gi = mean + std*eps
  #pragma unroll
  for (int i = 0; i < 4; ++i) {
    int lin = i * 512 + tid; int r = lin >> 6, j = lin & 63;
    float mean = co_f32[r * 324 + j];
    float sd   = co_f32[r * 324 + 64 + j];
    float e    = eps[(size_t)(row0 + r) * 64 + j];
    float g = mean + sd * e;
    out[(size_t)(row0 + r) * OUTP + 896 + j] = g;
    gi[(size_t)(row0 + r) * 64 + j] = f2bf(g);
  }
}

// ---- generator GRU + factor linear --------------------------------------------
// 32 rows/block, 8 waves. A_lds[32][584] = [h/rh/hnew(0:512) | Gi(512:576)].
#define GPITCH 584   // stride 1168B = 73 x16B groups, 73%8==1 -> conflict-free
__global__ __launch_bounds__(512, 4) void gen_kernel(
    const float* __restrict__ h0, const unsigned short* __restrict__ gi,
    const unsigned short* __restrict__ B1, const unsigned short* __restrict__ B2,
    const unsigned short* __restrict__ facw,
    const float* __restrict__ bih, const float* __restrict__ bhh,
    float* __restrict__ out)
{
  __shared__ unsigned short A[32 * GPITCH];
  const int tid = threadIdx.x;
  const int row0 = blockIdx.x * 32;

  // ---- stage h (32x512 f32 -> bf16) + Gi (32x64 bf16)
  #pragma unroll
  for (int i = 0; i < 8; ++i) {
    int lin = i * 512 + tid; int r = lin >> 7, c = (lin & 127) * 4;
    float4 v = *reinterpret_cast<const float4*>(&h0[(size_t)(row0 + r) * OUTP + c]);
    ushort4 o = { f2bf(v.x), f2bf(v.y), f2bf(v.z), f2bf(v.w) };
    *reinterpret_cast<ushort4*>(&A[r * GPITCH + c]) = o;
  }
  {
    int r = tid >> 4, c = (tid & 15) * 4;
    *reinterpret_cast<ushort4*>(&A[r * GPITCH + 512 + c]) =
        *reinterpret_cast<const ushort4*>(&gi[(size_t)(row0 + r) * 64 + c]);
  }
  __syncthreads();

  const int w = tid >> 6, lane = tid & 63;
  const int lc = lane & 31, lh = lane >> 5;
  const int kofs = lh * 8;

  // ---- phase 1: z, r  (K=576 over [h|Gi]) ; 2 N-tiles of 32 per wave
  f16x4 zreg[2][4], hreg[2][4];
  unsigned int rhp[2][8];
  #pragma unroll
  for (int nt = 0; nt < 2; ++nt) {
    const int jc = w * 64 + nt * 32 + lc;   // 0..511
    f32x16 zacc = {}, racc = {};
    #pragma unroll
    for (int kt = 0; kt < 36; ++kt) {
      int k0 = kt * 16 + kofs;
      s16x8 a  = ldb8(&A[lc * GPITCH + k0]);
      s16x8 bz = ldb8(&B1[(size_t)jc * 576 + k0]);
      s16x8 br = ldb8(&B1[(size_t)(512 + jc) * 576 + k0]);
      zacc = mfma32(a, bz, zacc);
      racc = mfma32(a, br, racc);
    }
    float bz_ = bih[jc] + bhh[jc];
    float br_ = bih[512 + jc] + bhh[512 + jc];
    #pragma unroll
    for (int v = 0; v < 16; ++v) {
      int rrow = ROW32(v, lh);
      float z  = sigm(zacc[v] + bz_);
      float rv = sigm(racc[v] + br_);
      float h  = bf2f(A[rrow * GPITCH + jc]);
      zreg[nt][v >> 2][v & 3] = (_Float16)z;
      hreg[nt][v >> 2][v & 3] = (_Float16)h;
      unsigned short rb = f2bf(rv * h);
      if (v & 1) rhp[nt][v >> 1] |= ((unsigned int)rb << 16);
      else       rhp[nt][v >> 1]  = rb;
    }
  }
  __syncthreads();
  #pragma unroll
  for (int nt = 0; nt < 2; ++nt) {
    const int jc = w * 64 + nt * 32 + lc;
    #pragma unroll
    for (int v = 0; v < 16; ++v) {
      int rrow = ROW32(v, lh);
      unsigned short rb = (v & 1) ? (unsigned short)(rhp[nt][v >> 1] >> 16)
                                  : (unsigned short)(rhp[nt][v >> 1] & 0xffffu);
      A[rrow * GPITCH + jc] = rb;
    }
  }
  __syncthreads();

  // ---- phase 2: n = tanh([rh|Gi] @ B2 + b) ; gate ; h_new
  #pragma unroll
  for (int nt = 0; nt < 2; ++nt) {
    const int jc = w * 64 + nt * 32 + lc;
    f32x16 acc0 = {}, acc1 = {};
    #pragma unroll
    for (int kt = 0; kt < 36; kt += 2) {
      int k0 = kt * 16 + kofs;
      s16x8 a0 = ldb8(&A[lc * GPITCH + k0]);
      s16x8 b0 = ldb8(&B2[(size_t)jc * 576 + k0]);
      acc0 = mfma32(a0, b0, acc0);
      s16x8 a1 = ldb8(&A[lc * GPITCH + k0 + 16]);
      s16x8 b1 = ldb8(&B2[(size_t)jc * 576 + k0 + 16]);
      acc1 = mfma32(a1, b1, acc1);
    }
    float bn_ = bih[1024 + jc] + bhh[1024 + jc];
    #pragma unroll
    for (int v = 0; v < 16; ++v) {
      int rrow = ROW32(v, lh);
      float n = tanh_(acc0[v] + acc1[v] + bn_);
      float z = (float)zreg[nt][v >> 2][v & 3];
      float h = (float)hreg[nt][v >> 2][v & 3];
      float hv = fminf(fmaxf(z * h + (1.f - z) * n, -5.f), 5.f);
      out[(size_t)(row0 + rrow) * OUTP + jc] = hv;
      unsigned short hb = f2bf(hv);
      if (v & 1) rhp[nt][v >> 1] = (rhp[nt][v >> 1] & 0x0000ffffu) | ((unsigned int)hb << 16);
      else       rhp[nt][v >> 1] = (rhp[nt][v >> 1] & 0xffff0000u) | hb;
    }
  }
  __syncthreads();
  #pragma unroll
  for (int nt = 0; nt < 2; ++nt) {
    const int jc = w * 64 + nt * 32 + lc;
    #pragma unroll
    for (int v = 0; v < 16; ++v) {
      int rrow = ROW32(v, lh);
      unsigned short hb = (v & 1) ? (unsigned short)(rhp[nt][v >> 1] >> 16)
                                  : (unsigned short)(rhp[nt][v >> 1] & 0xffffu);
      A[rrow * GPITCH + jc] = hb;
    }
  }
  __syncthreads();

  // ---- factor = h_new @ facW^T (K=512, N=128), 16x16x32 tiles
  {
    const int ln = lane & 15, lk = lane >> 4;
    const int jcf = w * 16 + ln;       // 0..127
    f32x4 fa[2] = {{0,0,0,0},{0,0,0,0}};
    #pragma unroll
    for (int kt = 0; kt < 16; ++kt) {
      int k0 = kt * 32 + lk * 8;
      s16x8 b = ldb8(&facw[(size_t)jcf * 512 + k0]);
      #pragma unroll
      for (int mt = 0; mt < 2; ++mt) {
        s16x8 a = ldb8(&A[(mt * 16 + ln) * GPITCH + k0]);
        fa[mt] = mfma16(a, b, fa[mt]);
      }
    }
    #pragma unroll
    for (int mt = 0; mt < 2; ++mt)
      #pragma unroll
      for (int rr = 0; rr < 4; ++rr)
        out[(size_t)(row0 + mt * 16 + lk * 4 + rr) * OUTP + 960 + jcf] = fa[mt][rr];
  }
}

extern "C" void kernel_launch(void* const* d_in, const int* in_sizes, int n_in,
                              void* d_out, int out_size, void* d_ws, size_t ws_size,
                              hipStream_t stream) {
  const float* input   = (const float*)d_in[0];
  const float* h0      = (const float*)d_in[1];
  const float* eps     = (const float*)d_in[2];
  const float* gen_Wih = (const float*)d_in[3];
  const float* gen_bih = (const float*)d_in[4];
  const float* gen_Whh = (const float*)d_in[5];
  const float* gen_bhh = (const float*)d_in[6];
  const float* con_Wih = (const float*)d_in[7];
  const float* con_bih = (const float*)d_in[8];
  const float* con_Whh = (const float*)d_in[9];
  const float* con_bhh = (const float*)d_in[10];
  const float* fac_W   = (const float*)d_in[11];
  const float* co_W    = (const float*)d_in[12];
  const float* co_b    = (const float*)d_in[13];
  float* out = (float*)d_out;

  unsigned short* ws = (unsigned short*)d_ws;
  unsigned short* w_conB1 = ws;                        // 512*640
  unsigned short* w_conB2 = w_conB1 + 512 * 640;       // 256*640
  unsigned short* w_genB1 = w_conB2 + 256 * 640;       // 1024*576
  unsigned short* w_genB2 = w_genB1 + 1024 * 576;      // 512*576
  unsigned short* w_coW   = w_genB2 + 512 * 576;       // 128*256
  unsigned short* w_facWn = w_coW + 128 * 256;         // 128*512
  unsigned short* w_gi    = w_facWn + 128 * 512;       // 32768*64

  conpack_kernel<<<768, 160, 0, stream>>>(con_Wih, con_Whh, w_conB1, w_conB2);
  genpack_kernel<<<1536, 144, 0, stream>>>(gen_Whh, gen_Wih, w_genB1, w_genB2);
  cvt_kernel<<<(128 * 256 / 4 + 255) / 256, 256, 0, stream>>>(co_W, w_coW, 128 * 256 / 4);
  facnorm_kernel<<<128, 64, 0, stream>>>(fac_W, w_facWn);

  con_kernel<<<1024, 512, 0, stream>>>(input, h0, eps, w_conB1, w_conB2, w_coW,
                                       con_bih, con_bhh, co_b, out, w_gi);
  gen_kernel<<<1024, 512, 0, stream>>>(h0, w_gi, w_genB1, w_genB2, w_facWn,
                                       gen_bih, gen_bhh, out);
}

// Round 3
// 434.337 us; speedup vs baseline: 1.8690x; 1.3061x over previous
//
#include <hip/hip_runtime.h>

// DecoderCell (LFADS-style) fused MI355X implementation, v3.
// v2 -> v3: explicit depth-4 software-pipelined B prefetch in all K-loops
// (VGPR=64 in v2 showed the compiler serialized loads); gen phase2 re-reads
// h from h0 global (drops hreg persist) to fit prefetch registers.

typedef short  s16x8  __attribute__((ext_vector_type(8)));
typedef float  f32x4  __attribute__((ext_vector_type(4)));
typedef float  f32x16 __attribute__((ext_vector_type(16)));
typedef _Float16 f16x4 __attribute__((ext_vector_type(4)));

#define OUTP 1088

__device__ __forceinline__ unsigned short f2bf(float f) {
  union { float f; unsigned int u; } v; v.f = f;
  unsigned int u = v.u;
  return (unsigned short)((u + 0x7FFFu + ((u >> 16) & 1u)) >> 16);  // RNE
}
__device__ __forceinline__ float bf2f(unsigned short b) {
  union { unsigned int u; float f; } v; v.u = ((unsigned int)b) << 16;
  return v.f;
}
__device__ __forceinline__ float sigm(float x) { return 1.f / (1.f + __expf(-x)); }
__device__ __forceinline__ float tanh_(float x) { return 2.f / (1.f + __expf(-2.f * x)) - 1.f; }

__device__ __forceinline__ f32x4 mfma16(s16x8 a, s16x8 b, f32x4 c) {
  return __builtin_amdgcn_mfma_f32_16x16x32_bf16(a, b, c, 0, 0, 0);
}
__device__ __forceinline__ f32x16 mfma32(s16x8 a, s16x8 b, f32x16 c) {
  return __builtin_amdgcn_mfma_f32_32x32x16_bf16(a, b, c, 0, 0, 0);
}
template <typename T>
__device__ __forceinline__ s16x8 ldb8(const T* p) {
  return *reinterpret_cast<const s16x8*>(p);
}

// ---- prep: f32 -> bf16 plain conversion -------------------------------------
__global__ void cvt_kernel(const float* __restrict__ src, unsigned short* __restrict__ dst, int n4) {
  int i = blockIdx.x * 256 + threadIdx.x;
  if (i >= n4) return;
  float4 v = reinterpret_cast<const float4*>(src)[i];
  ushort4 o;
  o.x = f2bf(v.x); o.y = f2bf(v.y); o.z = f2bf(v.z); o.w = f2bf(v.w);
  reinterpret_cast<ushort4*>(dst)[i] = o;
}

// ---- prep: row-L2-normalize fac_W (128x512) -> bf16 -------------------------
__global__ void facnorm_kernel(const float* __restrict__ w, unsigned short* __restrict__ dst) {
  int row = blockIdx.x;       // 128
  int lane = threadIdx.x;     // 64
  float v[8]; float s = 0.f;
  #pragma unroll
  for (int i = 0; i < 8; ++i) { v[i] = w[row * 512 + lane * 8 + i]; s += v[i] * v[i]; }
  #pragma unroll
  for (int off = 32; off; off >>= 1) s += __shfl_xor(s, off);
  float scale = 1.f / fmaxf(sqrtf(s), 1e-12f);
  #pragma unroll
  for (int i = 0; i < 8; ++i) dst[row * 512 + lane * 8 + i] = f2bf(v[i] * scale);
}

// ---- prep: pack gen weights ---------------------------------------------------
// genB1[1024][576]: row j<512: [Whh_z[j] | Wih_z[j]] ; row 512+j: r-gate.
// genB2[512][576]:  [Whh_n[j] | Wih_n[j]].
__global__ void genpack_kernel(const float* __restrict__ whh, const float* __restrict__ wih,
                               unsigned short* __restrict__ B1, unsigned short* __restrict__ B2) {
  int r = blockIdx.x;          // 0..1535
  int c4 = threadIdx.x * 4;    // 0..572
  float4 v;
  if (c4 < 512) v = *reinterpret_cast<const float4*>(&whh[(size_t)r * 512 + c4]);
  else          v = *reinterpret_cast<const float4*>(&wih[(size_t)r * 64 + (c4 - 512)]);
  ushort4 o; o.x = f2bf(v.x); o.y = f2bf(v.y); o.z = f2bf(v.z); o.w = f2bf(v.w);
  unsigned short* dst = (r < 1024) ? &B1[(size_t)r * 576 + c4]
                                   : &B2[(size_t)(r - 1024) * 576 + c4];
  *reinterpret_cast<ushort4*>(dst) = o;
}

// ---- prep: pack con weights ---------------------------------------------------
// K-order = [input(256) | h(256) | factor(128)].
// conB1[512][640] (z rows 0:256, r rows 256:512), conB2[256][640] (n).
__global__ void conpack_kernel(const float* __restrict__ wih, const float* __restrict__ whh,
                               unsigned short* __restrict__ B1, unsigned short* __restrict__ B2) {
  int r = blockIdx.x;          // 0..767
  int c4 = threadIdx.x * 4;    // 0..636
  float4 v;
  if (c4 < 256)      v = *reinterpret_cast<const float4*>(&wih[(size_t)r * 384 + c4]);
  else if (c4 < 512) v = *reinterpret_cast<const float4*>(&whh[(size_t)r * 256 + (c4 - 256)]);
  else               v = *reinterpret_cast<const float4*>(&wih[(size_t)r * 384 + (c4 - 256)]);
  ushort4 o; o.x = f2bf(v.x); o.y = f2bf(v.y); o.z = f2bf(v.z); o.w = f2bf(v.w);
  unsigned short* dst = (r < 512) ? &B1[(size_t)r * 640 + c4]
                                  : &B2[(size_t)(r - 512) * 640 + c4];
  *reinterpret_cast<ushort4*>(dst) = o;
}

#define ROW32(v, lh) (((v) & 3) + 8 * ((v) >> 2) + 4 * (lh))

// ---- controller GRU + co-linear + rsample -----------------------------------
// 32 rows/block, 8 waves. A_lds[32][648] = [input(0:256)|h/rh/hnew(256:512)|factor(512:640)].
#define CPITCH 648
__global__ __launch_bounds__(512, 4) void con_kernel(
    const float* __restrict__ input, const float* __restrict__ h0,
    const float* __restrict__ eps,
    const unsigned short* __restrict__ B1, const unsigned short* __restrict__ B2,
    const unsigned short* __restrict__ coW,
    const float* __restrict__ bih, const float* __restrict__ bhh,
    const float* __restrict__ cob,
    float* __restrict__ out, unsigned short* __restrict__ gi)
{
  __shared__ unsigned short A[32 * CPITCH];
  const int tid = threadIdx.x;
  const int row0 = blockIdx.x * 32;

  // ---- stage A = [input | h | factor] as bf16
  #pragma unroll
  for (int i = 0; i < 4; ++i) {   // input 32x256
    int lin = i * 512 + tid; int r = lin >> 6, c = (lin & 63) * 4;
    float4 v = *reinterpret_cast<const float4*>(&input[(size_t)(row0 + r) * 256 + c]);
    ushort4 o = { f2bf(v.x), f2bf(v.y), f2bf(v.z), f2bf(v.w) };
    *reinterpret_cast<ushort4*>(&A[r * CPITCH + c]) = o;
  }
  #pragma unroll
  for (int i = 0; i < 4; ++i) {   // h 32x256 (h0 cols 512:768)
    int lin = i * 512 + tid; int r = lin >> 6, c = (lin & 63) * 4;
    float4 v = *reinterpret_cast<const float4*>(&h0[(size_t)(row0 + r) * OUTP + 512 + c]);
    ushort4 o = { f2bf(v.x), f2bf(v.y), f2bf(v.z), f2bf(v.w) };
    *reinterpret_cast<ushort4*>(&A[r * CPITCH + 256 + c]) = o;
  }
  #pragma unroll
  for (int i = 0; i < 2; ++i) {   // factor 32x128 (h0 cols 960:1088)
    int lin = i * 512 + tid; int r = lin >> 5, c = (lin & 31) * 4;
    float4 v = *reinterpret_cast<const float4*>(&h0[(size_t)(row0 + r) * OUTP + 960 + c]);
    ushort4 o = { f2bf(v.x), f2bf(v.y), f2bf(v.z), f2bf(v.w) };
    *reinterpret_cast<ushort4*>(&A[r * CPITCH + 512 + c]) = o;
  }
  __syncthreads();

  const int w = tid >> 6, lane = tid & 63;
  const int lc = lane & 31, lh = lane >> 5;
  const int kofs = lh * 8;
  const int jc = w * 32 + lc;          // 0..255

  // ---- phase 1: z, r  (K=640 over [input|h|factor]), depth-4 B prefetch
  f16x4 zreg[4], hreg[4];
  unsigned int rhp[8];
  {
    const unsigned short* pz = B1 + (size_t)jc * 640 + kofs;
    const unsigned short* pr = B1 + (size_t)(256 + jc) * 640 + kofs;
    const unsigned short* pa = &A[lc * CPITCH + kofs];
    s16x8 bz0 = ldb8(pz),      br0 = ldb8(pr);
    s16x8 bz1 = ldb8(pz + 16), br1 = ldb8(pr + 16);
    f32x16 zacc = {}, racc = {};
    #pragma unroll
    for (int kt = 0; kt < 40; kt += 2) {
      s16x8 a0 = ldb8(pa + kt * 16);
      s16x8 a1 = ldb8(pa + kt * 16 + 16);
      s16x8 nz0, nr0, nz1, nr1;
      if (kt + 2 < 40) {
        nz0 = ldb8(pz + (kt + 2) * 16); nr0 = ldb8(pr + (kt + 2) * 16);
        nz1 = ldb8(pz + (kt + 3) * 16); nr1 = ldb8(pr + (kt + 3) * 16);
      }
      zacc = mfma32(a0, bz0, zacc);
      racc = mfma32(a0, br0, racc);
      zacc = mfma32(a1, bz1, zacc);
      racc = mfma32(a1, br1, racc);
      bz0 = nz0; br0 = nr0; bz1 = nz1; br1 = nr1;
    }
    float bz_ = bih[jc] + bhh[jc];
    float br_ = bih[256 + jc] + bhh[256 + jc];
    #pragma unroll
    for (int v = 0; v < 16; ++v) {
      int rrow = ROW32(v, lh);
      float z  = sigm(zacc[v] + bz_);
      float rv = sigm(racc[v] + br_);
      float h  = bf2f(A[rrow * CPITCH + 256 + jc]);
      zreg[v >> 2][v & 3] = (_Float16)z;
      hreg[v >> 2][v & 3] = (_Float16)h;
      unsigned short rb = f2bf(rv * h);
      if (v & 1) rhp[v >> 1] |= ((unsigned int)rb << 16);
      else       rhp[v >> 1]  = rb;
    }
  }
  __syncthreads();
  #pragma unroll
  for (int v = 0; v < 16; ++v) {   // rh overwrites h section
    int rrow = ROW32(v, lh);
    unsigned short rb = (v & 1) ? (unsigned short)(rhp[v >> 1] >> 16)
                                : (unsigned short)(rhp[v >> 1] & 0xffffu);
    A[rrow * CPITCH + 256 + jc] = rb;
  }
  __syncthreads();

  // ---- phase 2: n = tanh([input|rh|factor] @ B2 + b) ; gate; h_new
  {
    const unsigned short* pn = B2 + (size_t)jc * 640 + kofs;
    const unsigned short* pa = &A[lc * CPITCH + kofs];
    s16x8 b0 = ldb8(pn), b1 = ldb8(pn + 16);
    f32x16 acc0 = {}, acc1 = {};
    #pragma unroll
    for (int kt = 0; kt < 40; kt += 2) {
      s16x8 a0 = ldb8(pa + kt * 16);
      s16x8 a1 = ldb8(pa + kt * 16 + 16);
      s16x8 nb0, nb1;
      if (kt + 2 < 40) {
        nb0 = ldb8(pn + (kt + 2) * 16);
        nb1 = ldb8(pn + (kt + 3) * 16);
      }
      acc0 = mfma32(a0, b0, acc0);
      acc1 = mfma32(a1, b1, acc1);
      b0 = nb0; b1 = nb1;
    }
    float bn_ = bih[512 + jc] + bhh[512 + jc];
    #pragma unroll
    for (int v = 0; v < 16; ++v) {
      int rrow = ROW32(v, lh);
      float n = tanh_(acc0[v] + acc1[v] + bn_);
      float z = (float)zreg[v >> 2][v & 3];
      float h = (float)hreg[v >> 2][v & 3];
      float hv = fminf(fmaxf(z * h + (1.f - z) * n, -5.f), 5.f);
      out[(size_t)(row0 + rrow) * OUTP + 512 + jc] = hv;
      unsigned short hb = f2bf(hv);
      if (v & 1) rhp[v >> 1] = (rhp[v >> 1] & 0x0000ffffu) | ((unsigned int)hb << 16);
      else       rhp[v >> 1] = (rhp[v >> 1] & 0xffff0000u) | hb;
    }
  }
  __syncthreads();
  #pragma unroll
  for (int v = 0; v < 16; ++v) {   // h_new overwrites rh section
    int rrow = ROW32(v, lh);
    unsigned short hb = (v & 1) ? (unsigned short)(rhp[v >> 1] >> 16)
                                : (unsigned short)(rhp[v >> 1] & 0xffffu);
    A[rrow * CPITCH + 256 + jc] = hb;
  }
  __syncthreads();

  // ---- co-linear (K=256 over h_new), mean/std -> out + LDS f32 scratch
  float* co_f32 = reinterpret_cast<float*>(A);   // input section is dead
  {
    const int ln = lane & 15, lk = lane >> 4;
    const int jcc = w * 16 + ln;       // 0..127
    f32x4 acc[2] = {{0,0,0,0},{0,0,0,0}};
    #pragma unroll
    for (int kt = 0; kt < 8; ++kt) {
      int k0 = kt * 32 + lk * 8;
      s16x8 b = ldb8(&coW[(size_t)jcc * 256 + k0]);
      #pragma unroll
      for (int mt = 0; mt < 2; ++mt) {
        s16x8 a = ldb8(&A[(mt * 16 + ln) * CPITCH + 256 + k0]);
        acc[mt] = mfma16(a, b, acc[mt]);
      }
    }
    float cb = cob[jcc];
    #pragma unroll
    for (int mt = 0; mt < 2; ++mt) {
      #pragma unroll
      for (int rr = 0; rr < 4; ++rr) {
        int rrow = mt * 16 + lk * 4 + rr;
        float val = acc[mt][rr] + cb;
        if (jcc < 64) {   // mean
          out[(size_t)(row0 + rrow) * OUTP + 768 + jcc] = val;
          co_f32[rrow * 324 + jcc] = val;
        } else {          // std
          float sd = __expf(0.5f * val);
          out[(size_t)(row0 + rrow) * OUTP + 832 + (jcc - 64)] = sd;
          co_f32[rrow * 324 + jcc] = sd;
        }
      }
    }
  }
  __syncthreads();

  // ---- rsample: gi = mean + std*eps
  #pragma unroll
  for (int i = 0; i < 4; ++i) {
    int lin = i * 512 + tid; int r = lin >> 6, j = lin & 63;
    float mean = co_f32[r * 324 + j];
    float sd   = co_f32[r * 324 + 64 + j];
    float e    = eps[(size_t)(row0 + r) * 64 + j];
    float g = mean + sd * e;
    out[(size_t)(row0 + r) * OUTP + 896 + j] = g;
    gi[(size_t)(row0 + r) * 64 + j] = f2bf(g);
  }
}

// ---- generator GRU + factor linear --------------------------------------------
// 32 rows/block, 8 waves. A_lds[32][584] = [h/rh/hnew(0:512) | Gi(512:576)].
#define GPITCH 584
__global__ __launch_bounds__(512, 3) void gen_kernel(
    const float* __restrict__ h0, const unsigned short* __restrict__ gi,
    const unsigned short* __restrict__ B1, const unsigned short* __restrict__ B2,
    const unsigned short* __restrict__ facw,
    const float* __restrict__ bih, const float* __restrict__ bhh,
    float* __restrict__ out)
{
  __shared__ unsigned short A[32 * GPITCH];
  const int tid = threadIdx.x;
  const int row0 = blockIdx.x * 32;

  // ---- stage h (32x512 f32 -> bf16) + Gi (32x64 bf16)
  #pragma unroll
  for (int i = 0; i < 8; ++i) {
    int lin = i * 512 + tid; int r = lin >> 7, c = (lin & 127) * 4;
    float4 v = *reinterpret_cast<const float4*>(&h0[(size_t)(row0 + r) * OUTP + c]);
    ushort4 o = { f2bf(v.x), f2bf(v.y), f2bf(v.z), f2bf(v.w) };
    *reinterpret_cast<ushort4*>(&A[r * GPITCH + c]) = o;
  }
  {
    int r = tid >> 4, c = (tid & 15) * 4;
    *reinterpret_cast<ushort4*>(&A[r * GPITCH + 512 + c]) =
        *reinterpret_cast<const ushort4*>(&gi[(size_t)(row0 + r) * 64 + c]);
  }
  __syncthreads();

  const int w = tid >> 6, lane = tid & 63;
  const int lc = lane & 31, lh = lane >> 5;
  const int kofs = lh * 8;

  // ---- phase 1: z, r  (K=576 over [h|Gi]); depth-4 B prefetch; 2 N-tiles/wave
  f16x4 zreg[2][4];
  unsigned int rhp[2][8];
  #pragma unroll
  for (int nt = 0; nt < 2; ++nt) {
    const int jc = w * 64 + nt * 32 + lc;   // 0..511
    const unsigned short* pz = B1 + (size_t)jc * 576 + kofs;
    const unsigned short* pr = B1 + (size_t)(512 + jc) * 576 + kofs;
    const unsigned short* pa = &A[lc * GPITCH + kofs];
    s16x8 bz0 = ldb8(pz),      br0 = ldb8(pr);
    s16x8 bz1 = ldb8(pz + 16), br1 = ldb8(pr + 16);
    f32x16 zacc = {}, racc = {};
    #pragma unroll
    for (int kt = 0; kt < 36; kt += 2) {
      s16x8 a0 = ldb8(pa + kt * 16);
      s16x8 a1 = ldb8(pa + kt * 16 + 16);
      s16x8 nz0, nr0, nz1, nr1;
      if (kt + 2 < 36) {
        nz0 = ldb8(pz + (kt + 2) * 16); nr0 = ldb8(pr + (kt + 2) * 16);
        nz1 = ldb8(pz + (kt + 3) * 16); nr1 = ldb8(pr + (kt + 3) * 16);
      }
      zacc = mfma32(a0, bz0, zacc);
      racc = mfma32(a0, br0, racc);
      zacc = mfma32(a1, bz1, zacc);
      racc = mfma32(a1, br1, racc);
      bz0 = nz0; br0 = nr0; bz1 = nz1; br1 = nr1;
    }
    float bz_ = bih[jc] + bhh[jc];
    float br_ = bih[512 + jc] + bhh[512 + jc];
    #pragma unroll
    for (int v = 0; v < 16; ++v) {
      int rrow = ROW32(v, lh);
      float z  = sigm(zacc[v] + bz_);
      float rv = sigm(racc[v] + br_);
      float h  = bf2f(A[rrow * GPITCH + jc]);
      zreg[nt][v >> 2][v & 3] = (_Float16)z;
      unsigned short rb = f2bf(rv * h);
      if (v & 1) rhp[nt][v >> 1] |= ((unsigned int)rb << 16);
      else       rhp[nt][v >> 1]  = rb;
    }
  }
  __syncthreads();
  #pragma unroll
  for (int nt = 0; nt < 2; ++nt) {
    const int jc = w * 64 + nt * 32 + lc;
    #pragma unroll
    for (int v = 0; v < 16; ++v) {
      int rrow = ROW32(v, lh);
      unsigned short rb = (v & 1) ? (unsigned short)(rhp[nt][v >> 1] >> 16)
                                  : (unsigned short)(rhp[nt][v >> 1] & 0xffffu);
      A[rrow * GPITCH + jc] = rb;
    }
  }
  __syncthreads();

  // ---- phase 2: n = tanh([rh|Gi] @ B2 + b) ; gate ; h_new
  #pragma unroll
  for (int nt = 0; nt < 2; ++nt) {
    const int jc = w * 64 + nt * 32 + lc;
    const unsigned short* pn = B2 + (size_t)jc * 576 + kofs;
    const unsigned short* pa = &A[lc * GPITCH + kofs];
    // hoist h re-reads (f32, coalesced 128B per half-wave) above the K-loop
    f32x4 hbuf[4];
    #pragma unroll
    for (int v = 0; v < 16; ++v)
      hbuf[v >> 2][v & 3] = h0[(size_t)(row0 + ROW32(v, lh)) * OUTP + jc];
    s16x8 b0 = ldb8(pn), b1 = ldb8(pn + 16);
    f32x16 acc0 = {}, acc1 = {};
    #pragma unroll
    for (int kt = 0; kt < 36; kt += 2) {
      s16x8 a0 = ldb8(pa + kt * 16);
      s16x8 a1 = ldb8(pa + kt * 16 + 16);
      s16x8 nb0, nb1;
      if (kt + 2 < 36) {
        nb0 = ldb8(pn + (kt + 2) * 16);
        nb1 = ldb8(pn + (kt + 3) * 16);
      }
      acc0 = mfma32(a0, b0, acc0);
      acc1 = mfma32(a1, b1, acc1);
      b0 = nb0; b1 = nb1;
    }
    float bn_ = bih[1024 + jc] + bhh[1024 + jc];
    #pragma unroll
    for (int v = 0; v < 16; ++v) {
      int rrow = ROW32(v, lh);
      float n = tanh_(acc0[v] + acc1[v] + bn_);
      float z = (float)zreg[nt][v >> 2][v & 3];
      float h = hbuf[v >> 2][v & 3];
      float hv = fminf(fmaxf(z * h + (1.f - z) * n, -5.f), 5.f);
      out[(size_t)(row0 + rrow) * OUTP + jc] = hv;
      unsigned short hb = f2bf(hv);
      if (v & 1) rhp[nt][v >> 1] = (rhp[nt][v >> 1] & 0x0000ffffu) | ((unsigned int)hb << 16);
      else       rhp[nt][v >> 1] = (rhp[nt][v >> 1] & 0xffff0000u) | hb;
    }
  }
  __syncthreads();
  #pragma unroll
  for (int nt = 0; nt < 2; ++nt) {
    const int jc = w * 64 + nt * 32 + lc;
    #pragma unroll
    for (int v = 0; v < 16; ++v) {
      int rrow = ROW32(v, lh);
      unsigned short hb = (v & 1) ? (unsigned short)(rhp[nt][v >> 1] >> 16)
                                  : (unsigned short)(rhp[nt][v >> 1] & 0xffffu);
      A[rrow * GPITCH + jc] = hb;
    }
  }
  __syncthreads();

  // ---- factor = h_new @ facW^T (K=512, N=128), 16x16x32 tiles
  {
    const int ln = lane & 15, lk = lane >> 4;
    const int jcf = w * 16 + ln;       // 0..127
    const unsigned short* pf = facw + (size_t)jcf * 512;
    f32x4 fa[2] = {{0,0,0,0},{0,0,0,0}};
    #pragma unroll
    for (int kt = 0; kt < 16; ++kt) {
      int k0 = kt * 32 + lk * 8;
      s16x8 b = ldb8(pf + k0);
      #pragma unroll
      for (int mt = 0; mt < 2; ++mt) {
        s16x8 a = ldb8(&A[(mt * 16 + ln) * GPITCH + k0]);
        fa[mt] = mfma16(a, b, fa[mt]);
      }
    }
    #pragma unroll
    for (int mt = 0; mt < 2; ++mt)
      #pragma unroll
      for (int rr = 0; rr < 4; ++rr)
        out[(size_t)(row0 + mt * 16 + lk * 4 + rr) * OUTP + 960 + jcf] = fa[mt][rr];
  }
}

extern "C" void kernel_launch(void* const* d_in, const int* in_sizes, int n_in,
                              void* d_out, int out_size, void* d_ws, size_t ws_size,
                              hipStream_t stream) {
  const float* input   = (const float*)d_in[0];
  const float* h0      = (const float*)d_in[1];
  const float* eps     = (const float*)d_in[2];
  const float* gen_Wih = (const float*)d_in[3];
  const float* gen_bih = (const float*)d_in[4];
  const float* gen_Whh = (const float*)d_in[5];
  const float* gen_bhh = (const float*)d_in[6];
  const float* con_Wih = (const float*)d_in[7];
  const float* con_bih = (const float*)d_in[8];
  const float* con_Whh = (const float*)d_in[9];
  const float* con_bhh = (const float*)d_in[10];
  const float* fac_W   = (const float*)d_in[11];
  const float* co_W    = (const float*)d_in[12];
  const float* co_b    = (const float*)d_in[13];
  float* out = (float*)d_out;

  unsigned short* ws = (unsigned short*)d_ws;
  unsigned short* w_conB1 = ws;                        // 512*640
  unsigned short* w_conB2 = w_conB1 + 512 * 640;       // 256*640
  unsigned short* w_genB1 = w_conB2 + 256 * 640;       // 1024*576
  unsigned short* w_genB2 = w_genB1 + 1024 * 576;      // 512*576
  unsigned short* w_coW   = w_genB2 + 512 * 576;       // 128*256
  unsigned short* w_facWn = w_coW + 128 * 256;         // 128*512
  unsigned short* w_gi    = w_facWn + 128 * 512;       // 32768*64

  conpack_kernel<<<768, 160, 0, stream>>>(con_Wih, con_Whh, w_conB1, w_conB2);
  genpack_kernel<<<1536, 144, 0, stream>>>(gen_Whh, gen_Wih, w_genB1, w_genB2);
  cvt_kernel<<<(128 * 256 / 4 + 255) / 256, 256, 0, stream>>>(co_W, w_coW, 128 * 256 / 4);
  facnorm_kernel<<<128, 64, 0, stream>>>(fac_W, w_facWn);

  con_kernel<<<1024, 512, 0, stream>>>(input, h0, eps, w_conB1, w_conB2, w_coW,
                                       con_bih, con_bhh, co_b, out, w_gi);
  gen_kernel<<<1024, 512, 0, stream>>>(h0, w_gi, w_genB1, w_genB2, w_facWn,
                                       gen_bih, gen_bhh, out);
}

// Round 4
// 408.997 us; speedup vs baseline: 1.9848x; 1.0620x over previous
//
#include <hip/hip_runtime.h>

// DecoderCell v4: split into 6 M-tiled MFMA GEMMs (m97-style 128x128xBK64,
// global_load_lds staging) with fused gate epilogues. v3's fused design had
// M=32 rows per B-read -> B-issue-bound at 8% MfmaUtil.
//
// h_0 layout: [gen 0:512 | con 512:768 | mean 768:832 | std 832:896 | gi 896:960 | factor 960:1088]
// A_con[32768][640] = [input 256 | factor 128 | h_con->hnew_con 256]
// A_gen[32768][576] = [gi 64 | h_gen->hnew_gen 512]

typedef short  s16x8 __attribute__((ext_vector_type(8)));
typedef float  f32x4 __attribute__((ext_vector_type(4)));
typedef unsigned short ush;

#define OUTP 1088
#define NROW 32768

__device__ __forceinline__ ush f2bf(float f) {
  union { float f; unsigned int u; } v; v.f = f;
  unsigned int u = v.u;
  return (ush)((u + 0x7FFFu + ((u >> 16) & 1u)) >> 16);  // RNE
}
__device__ __forceinline__ float bf2f(ush b) {
  union { unsigned int u; float f; } v; v.u = ((unsigned int)b) << 16;
  return v.f;
}
__device__ __forceinline__ float sigm(float x) { return 1.f / (1.f + __expf(-x)); }
__device__ __forceinline__ float tanh_(float x) { return 2.f / (1.f + __expf(-2.f * x)) - 1.f; }

__device__ __forceinline__ f32x4 mfma16(s16x8 a, s16x8 b, f32x4 c) {
  return __builtin_amdgcn_mfma_f32_16x16x32_bf16(a, b, c, 0, 0, 0);
}
__device__ __forceinline__ s16x8 ldb8(const ush* p) {
  return *reinterpret_cast<const s16x8*>(p);
}
// async global->LDS, 16B per lane; LDS dest = uniform base + lane*16
__device__ __forceinline__ void gld16(const ush* g, ush* l) {
  __builtin_amdgcn_global_load_lds(
      (const __attribute__((address_space(1))) unsigned int*)g,
      (__attribute__((address_space(3))) unsigned int*)l, 16, 0, 0);
}
__device__ __forceinline__ ushort4 pack4(float4 a) {
  ushort4 o; o.x = f2bf(a.x); o.y = f2bf(a.y); o.z = f2bf(a.z); o.w = f2bf(a.w);
  return o;
}

// ---- prep: A_con = [input | factor | h_con] bf16 ---------------------------
__global__ void prepAcon_kernel(const float* __restrict__ in, const float* __restrict__ h0,
                                ush* __restrict__ A) {
  int t = blockIdx.x * 256 + threadIdx.x;      // 32768*80
  int row = t / 80, c8 = (t % 80) * 8;
  const float* src;
  if (c8 < 256)      src = &in[(size_t)row * 256 + c8];
  else if (c8 < 384) src = &h0[(size_t)row * OUTP + 960 + (c8 - 256)];
  else               src = &h0[(size_t)row * OUTP + 512 + (c8 - 384)];
  float4 a = *reinterpret_cast<const float4*>(src);
  float4 b = *reinterpret_cast<const float4*>(src + 4);
  ushort4* d = reinterpret_cast<ushort4*>(&A[(size_t)row * 640 + c8]);
  d[0] = pack4(a); d[1] = pack4(b);
}

// ---- prep: A_gen cols 64..575 = h_gen bf16 ---------------------------------
__global__ void prepAgen_kernel(const float* __restrict__ h0, ush* __restrict__ A) {
  int t = blockIdx.x * 256 + threadIdx.x;      // 32768*64
  int row = t >> 6, c8 = (t & 63) * 8;
  float4 a = *reinterpret_cast<const float4*>(&h0[(size_t)row * OUTP + c8]);
  float4 b = *reinterpret_cast<const float4*>(&h0[(size_t)row * OUTP + c8 + 4]);
  ushort4* d = reinterpret_cast<ushort4*>(&A[(size_t)row * 576 + 64 + c8]);
  d[0] = pack4(a); d[1] = pack4(b);
}

// ---- prep: pack con weights: row r -> [Wih(384) | Whh(256)] ----------------
__global__ void packBcon_kernel(const float* __restrict__ wih, const float* __restrict__ whh,
                                ush* __restrict__ B1, ush* __restrict__ B2) {
  int r = blockIdx.x;          // 0..767
  int c4 = threadIdx.x * 4;    // 0..636
  float4 v = (c4 < 384) ? *reinterpret_cast<const float4*>(&wih[(size_t)r * 384 + c4])
                        : *reinterpret_cast<const float4*>(&whh[(size_t)r * 256 + (c4 - 384)]);
  ush* dst = (r < 512) ? &B1[(size_t)r * 640 + c4] : &B2[(size_t)(r - 512) * 640 + c4];
  *reinterpret_cast<ushort4*>(dst) = pack4(v);
}

// ---- prep: pack gen weights: row r -> [Wih(64) | Whh(512)] -----------------
__global__ void packBgen_kernel(const float* __restrict__ wih, const float* __restrict__ whh,
                                ush* __restrict__ B1, ush* __restrict__ B2) {
  int r = blockIdx.x;          // 0..1535
  int c4 = threadIdx.x * 4;    // 0..572
  float4 v = (c4 < 64) ? *reinterpret_cast<const float4*>(&wih[(size_t)r * 64 + c4])
                       : *reinterpret_cast<const float4*>(&whh[(size_t)r * 512 + (c4 - 64)]);
  ush* dst = (r < 1024) ? &B1[(size_t)r * 576 + c4] : &B2[(size_t)(r - 1024) * 576 + c4];
  *reinterpret_cast<ushort4*>(dst) = pack4(v);
}

// ---- prep: co_W f32->bf16 --------------------------------------------------
__global__ void cvt_kernel(const float* __restrict__ src, ush* __restrict__ dst, int n4) {
  int i = blockIdx.x * 256 + threadIdx.x;
  if (i >= n4) return;
  float4 v = reinterpret_cast<const float4*>(src)[i];
  reinterpret_cast<ushort4*>(dst)[i] = pack4(v);
}

// ---- prep: row-L2-normalize fac_W (128x512) -> bf16 ------------------------
__global__ void facnorm_kernel(const float* __restrict__ w, ush* __restrict__ dst) {
  int row = blockIdx.x;       // 128
  int lane = threadIdx.x;     // 64
  float v[8]; float s = 0.f;
  #pragma unroll
  for (int i = 0; i < 8; ++i) { v[i] = w[row * 512 + lane * 8 + i]; s += v[i] * v[i]; }
  #pragma unroll
  for (int off = 32; off; off >>= 1) s += __shfl_xor(s, off);
  float scale = 1.f / fmaxf(sqrtf(s), 1e-12f);
  #pragma unroll
  for (int i = 0; i < 8; ++i) dst[row * 512 + lane * 8 + i] = f2bf(v[i] * scale);
}

// ---- rsample: gi = mean + std*eps; also fill A_gen gi section --------------
__global__ void rsample_kernel(const float* __restrict__ eps, float* __restrict__ out,
                               ush* __restrict__ Agen) {
  int t = blockIdx.x * 256 + threadIdx.x;      // 32768*64
  int m = t >> 6, j = t & 63;
  float mean = out[(size_t)m * OUTP + 768 + j];
  float sd   = out[(size_t)m * OUTP + 832 + j];
  float g = mean + sd * eps[(size_t)m * 64 + j];
  out[(size_t)m * OUTP + 896 + j] = g;
  Agen[(size_t)m * 576 + j] = f2bf(g);
}

// ---- the GEMM: 128x128 tile, BK=64, 256 threads / 4 waves ------------------
// EPI: 0 = zr-gate (store z bf16, rh bf16), 1 = n-gate (h_new -> out f32 + bf16),
//      2 = co (mean/std -> out), 3 = factor (plain f32 -> out)
template<int EPI, int KTOT, int KA1, int SA1, int SA2, int SB,
         int NT, int NHALF, int HOFS, int OOFS, int SHN>
__global__ __launch_bounds__(256, 3) void gemm_kernel(
    const ush* __restrict__ A1, const ush* __restrict__ A2,
    const ush* __restrict__ B,
    const float* __restrict__ bih, const float* __restrict__ bhh,
    const float* __restrict__ h0,
    const ush* __restrict__ zbuf,
    ush* __restrict__ st1, ush* __restrict__ st2,
    float* __restrict__ out)
{
  __shared__ ush As[128 * 64];
  __shared__ ush Bs[128 * 64];
  const int nwg = gridDim.x;
  const int wg = (blockIdx.x & 7) * (nwg >> 3) + (blockIdx.x >> 3);  // XCD-chunked
  const int mt = wg / NT, nt = wg % NT;
  const int m0 = mt * 128, n0 = nt * 128;
  const int tid = threadIdx.x;
  const int w = tid >> 6, lane = tid & 63;
  const int ln = lane & 15, lk = lane >> 4;
  const int wm = w >> 1, wn = w & 1;
  const int srow = lane >> 3;          // staging: lane -> row within 8-row strip
  const int scol = (lane & 7) * 8;     //          lane -> col (elements)

  f32x4 acc[4][4] = {};

  for (int ks = 0; ks < KTOT / 64; ++ks) {
    const int k0 = ks * 64;
    const ush* Ab; int sa, kk;
    if (k0 < KA1) { Ab = A1; sa = SA1; kk = k0; }
    else          { Ab = A2; sa = SA2; kk = k0 - KA1; }
    #pragma unroll
    for (int p = 0; p < 4; ++p) {
      int r0 = p * 32 + w * 8;
      gld16(Ab + (size_t)(m0 + r0 + srow) * sa + kk + scol, &As[r0 * 64]);
    }
    #pragma unroll
    for (int p = 0; p < 4; ++p) {
      int r0 = p * 32 + w * 8;
      gld16(B + (size_t)(n0 + r0 + srow) * SB + k0 + scol, &Bs[r0 * 64]);
    }
    asm volatile("s_waitcnt vmcnt(0)" ::: "memory");
    __syncthreads();
    #pragma unroll
    for (int kk2 = 0; kk2 < 2; ++kk2) {
      const int kb = kk2 * 32 + lk * 8;
      s16x8 af[4], bf[4];
      #pragma unroll
      for (int i = 0; i < 4; ++i) af[i] = ldb8(&As[(wm * 64 + i * 16 + ln) * 64 + kb]);
      #pragma unroll
      for (int i = 0; i < 4; ++i) bf[i] = ldb8(&Bs[(wn * 64 + i * 16 + ln) * 64 + kb]);
      #pragma unroll
      for (int i = 0; i < 4; ++i)
        #pragma unroll
        for (int j = 0; j < 4; ++j)
          acc[i][j] = mfma16(af[i], bf[j], acc[i][j]);
    }
    __syncthreads();
  }

  #pragma unroll
  for (int i = 0; i < 4; ++i) {
    #pragma unroll
    for (int j = 0; j < 4; ++j) {
      const int jg = n0 + wn * 64 + j * 16 + ln;       // packed-N col
      const int mb = m0 + wm * 64 + i * 16 + lk * 4;   // first of 4 rows
      if constexpr (EPI == 0) {          // z | r gates
        float bb = bih[jg] + bhh[jg];
        if (jg < NHALF) {
          #pragma unroll
          for (int r = 0; r < 4; ++r)
            st1[(size_t)(mb + r) * NHALF + jg] = f2bf(sigm(acc[i][j][r] + bb));
        } else {
          int jr = jg - NHALF;
          #pragma unroll
          for (int r = 0; r < 4; ++r) {
            float rv = sigm(acc[i][j][r] + bb);
            float h = h0[(size_t)(mb + r) * OUTP + HOFS + jr];
            st2[(size_t)(mb + r) * NHALF + jr] = f2bf(rv * h);
          }
        }
      } else if constexpr (EPI == 1) {   // n gate + combine
        float bb = bih[2 * NHALF + jg] + bhh[2 * NHALF + jg];
        #pragma unroll
        for (int r = 0; r < 4; ++r) {
          float n = tanh_(acc[i][j][r] + bb);
          float z = bf2f(zbuf[(size_t)(mb + r) * NHALF + jg]);
          float h = h0[(size_t)(mb + r) * OUTP + HOFS + jg];
          float hv = fminf(fmaxf(z * h + (1.f - z) * n, -5.f), 5.f);
          out[(size_t)(mb + r) * OUTP + OOFS + jg] = hv;
          st1[(size_t)(mb + r) * SHN + jg] = f2bf(hv);
        }
      } else if constexpr (EPI == 2) {   // co: mean | logvar->std
        float bb = bih[jg];
        #pragma unroll
        for (int r = 0; r < 4; ++r) {
          float v = acc[i][j][r] + bb;
          if (jg < 64) out[(size_t)(mb + r) * OUTP + 768 + jg] = v;
          else         out[(size_t)(mb + r) * OUTP + 832 + (jg - 64)] = __expf(0.5f * v);
        }
      } else {                           // factor
        #pragma unroll
        for (int r = 0; r < 4; ++r)
          out[(size_t)(mb + r) * OUTP + 960 + jg] = acc[i][j][r];
      }
    }
  }
}

extern "C" void kernel_launch(void* const* d_in, const int* in_sizes, int n_in,
                              void* d_out, int out_size, void* d_ws, size_t ws_size,
                              hipStream_t stream) {
  const float* input   = (const float*)d_in[0];
  const float* h0      = (const float*)d_in[1];
  const float* eps     = (const float*)d_in[2];
  const float* gen_Wih = (const float*)d_in[3];
  const float* gen_bih = (const float*)d_in[4];
  const float* gen_Whh = (const float*)d_in[5];
  const float* gen_bhh = (const float*)d_in[6];
  const float* con_Wih = (const float*)d_in[7];
  const float* con_bih = (const float*)d_in[8];
  const float* con_Whh = (const float*)d_in[9];
  const float* con_bhh = (const float*)d_in[10];
  const float* fac_W   = (const float*)d_in[11];
  const float* co_W    = (const float*)d_in[12];
  const float* co_b    = (const float*)d_in[13];
  float* out = (float*)d_out;

  ush* ws = (ush*)d_ws;
  ush* A_gen  = ws;                                  // 32768*576 = 18,874,368
  ush* A_con  = A_gen + (size_t)NROW * 576;          // 32768*640 = 20,971,520
  ush* z_con  = A_con + (size_t)NROW * 640;          // 32768*256
  ush* rh_con = z_con + (size_t)NROW * 256;          // 32768*256
  ush* B1c    = rh_con + (size_t)NROW * 256;         // 512*640
  ush* B2c    = B1c + 512 * 640;                     // 256*640
  ush* B1g    = B2c + 256 * 640;                     // 1024*576
  ush* B2g    = B1g + 1024 * 576;                    // 512*576
  ush* coWb   = B2g + 512 * 576;                     // 128*256
  ush* facWn  = coWb + 128 * 256;                    // 128*512
  // aliases over dead con-phase buffers (gen phase runs after co/rsample):
  ush* z_gen  = A_con;                               // 32768*512 <= A_con size
  ush* rh_gen = z_con;                               // 32768*512 == z_con+rh_con

  // ---- prep (independent) ----
  packBcon_kernel<<<768, 160, 0, stream>>>(con_Wih, con_Whh, B1c, B2c);
  packBgen_kernel<<<1536, 144, 0, stream>>>(gen_Wih, gen_Whh, B1g, B2g);
  cvt_kernel<<<32, 256, 0, stream>>>(co_W, coWb, 128 * 256 / 4);
  facnorm_kernel<<<128, 64, 0, stream>>>(fac_W, facWn);
  prepAcon_kernel<<<10240, 256, 0, stream>>>(input, h0, A_con);
  prepAgen_kernel<<<8192, 256, 0, stream>>>(h0, A_gen);

  // ---- controller: z,r -> rh ; n -> h_new ; co ; rsample ----
  gemm_kernel<0, 640, 640, 640, 640, 640, 4, 256, 512, 0, 0>
      <<<1024, 256, 0, stream>>>(A_con, A_con, B1c, con_bih, con_bhh, h0,
                                 nullptr, z_con, rh_con, out);
  gemm_kernel<1, 640, 384, 640, 256, 640, 2, 256, 512, 512, 640>
      <<<512, 256, 0, stream>>>(A_con, rh_con, B2c, con_bih, con_bhh, h0,
                                z_con, A_con + 384, nullptr, out);
  gemm_kernel<2, 256, 256, 640, 640, 256, 1, 64, 0, 0, 0>
      <<<256, 256, 0, stream>>>(A_con + 384, A_con + 384, coWb, co_b, co_b, h0,
                                nullptr, nullptr, nullptr, out);
  rsample_kernel<<<8192, 256, 0, stream>>>(eps, out, A_gen);

  // ---- generator: z,r -> rh ; n -> h_new ; factor ----
  gemm_kernel<0, 576, 576, 576, 576, 576, 8, 512, 0, 0, 0>
      <<<2048, 256, 0, stream>>>(A_gen, A_gen, B1g, gen_bih, gen_bhh, h0,
                                 nullptr, z_gen, rh_gen, out);
  gemm_kernel<1, 576, 64, 576, 512, 576, 4, 512, 0, 0, 576>
      <<<1024, 256, 0, stream>>>(A_gen, rh_gen, B2g, gen_bih, gen_bhh, h0,
                                 z_gen, A_gen + 64, nullptr, out);
  gemm_kernel<3, 512, 512, 576, 576, 512, 1, 0, 0, 0, 0>
      <<<256, 256, 0, stream>>>(A_gen + 64, A_gen + 64, facWn, gen_bih, gen_bhh, h0,
                                nullptr, nullptr, nullptr, out);
}